// Round 5
// baseline (1536.269 us; speedup 1.0000x reference)
//
#include <hip/hip_runtime.h>

#define HID 128
#define CELLS 98304
#define NE 250000
#define NSTEPS 2

typedef __attribute__((ext_vector_type(8))) short short8;
typedef __attribute__((ext_vector_type(4))) float f32x4;
typedef unsigned short u16;

// pi permutation: stored slot s holds natural feature perm(s)
__device__ __forceinline__ int permf(int s) { return ((s & 7) << 4) | (s >> 3); }

__device__ __forceinline__ u16 f2bf(float f) {
  unsigned int u = __builtin_bit_cast(unsigned int, f);
  u += 0x7fffu + ((u >> 16) & 1u);
  return (u16)(u >> 16);
}
__device__ __forceinline__ float bf2f(u16 s) {
  unsigned int u = ((unsigned int)s) << 16;
  return __builtin_bit_cast(float, u);
}
__device__ __forceinline__ float sigm(float x) { return 1.f / (1.f + __expf(-x)); }
__device__ __forceinline__ float tanha(float x) { return 1.f - 2.f / (__expf(2.f * x) + 1.f); }

// ---------------- prep: bf16-convert + pi-permute all weights ----------------
__global__ void prep_kernel(
    const float* __restrict__ W0, const float* __restrict__ W1,
    const float* __restrict__ W2, const float* __restrict__ W3,
    const float* __restrict__ b0, const float* __restrict__ b1,
    const float* __restrict__ b2, const float* __restrict__ b3,
    const float* __restrict__ Wih, const float* __restrict__ Whh,
    const float* __restrict__ embed, const float* __restrict__ sw,
    u16* __restrict__ W0b, u16* __restrict__ W1b,
    u16* __restrict__ W2b, u16* __restrict__ W3b,
    u16* __restrict__ Wcb, float* __restrict__ bp,
    u16* __restrict__ embp, float* __restrict__ swp)
{
  int idx = blockIdx.x * 256 + threadIdx.x;
  if (idx < 65536) {  // W0b [et][n][s], s in [0,256): k_nat = perm on each 128-half
    int s = idx & 255, n = (idx >> 8) & 127, et = idx >> 15;
    int k = (s < 128) ? permf(s) : (128 + permf(s & 127));
    W0b[idx] = f2bf(W0[(et * 128 + n) * 256 + k]);
    return;
  }
  idx -= 65536;
  if (idx < 98304) {  // W1b/W2b/W3b [et][n][s]
    int which = idx >> 15, r = idx & 32767;
    int s = r & 127, n = (r >> 7) & 127, et = r >> 14;
    const float* W = which == 0 ? W1 : (which == 1 ? W2 : W3);
    u16* Wb = which == 0 ? W1b : (which == 1 ? W2b : W3b);
    Wb[r] = f2bf(W[(et * 128 + n) * 128 + permf(s)]);
    return;
  }
  idx -= 98304;
  if (idx < 262144) {  // Wcat [n=512][s=512] = [Wih(x|m0|m1) | Whh], per-128-block perm
    int s = idx & 511, n = idx >> 9;
    int blk = s >> 7, s7 = s & 127;
    float v = (blk < 3) ? Wih[n * 384 + blk * 128 + permf(s7)] : Whh[n * 128 + permf(s7)];
    Wcb[idx] = f2bf(v);
    return;
  }
  idx -= 262144;
  if (idx < 1024) {  // biases [layer 0..3][et][s] pi-order
    int l = idx >> 8, r = idx & 255;
    int et = r >> 7, s = r & 127;
    const float* b = l == 0 ? b0 : (l == 1 ? b1 : (l == 2 ? b2 : b3));
    bp[idx] = b[et * 128 + permf(s)];
    return;
  }
  idx -= 1024;
  if (idx < 384) {  // embed pi-order bf16
    int v = idx >> 7, s = idx & 127;
    embp[idx] = f2bf(embed[v * 128 + permf(s)]);
    return;
  }
  idx -= 384;
  if (idx < 128) swp[idx] = sw[permf(idx)];
}

// ---------------- init: x = embed[q] (pi, bf16), h = x, rc = 0 ----------------
__global__ void init_kernel(const int* __restrict__ q, const u16* __restrict__ embp,
                            u16* __restrict__ xb, u16* __restrict__ h, float* __restrict__ rc)
{
  int idx = blockIdx.x * 256 + threadIdx.x;
  int c = idx >> 7, s = idx & 127;
  u16 v = embp[q[c] * 128 + s];
  xb[idx] = v;
  h[idx] = v;
  rc[idx] = 0.f;
}

// ---------------- dst-sort pipeline: hist -> scan (2-level) -> scatter ----------------
__global__ void hist_kernel(const int* __restrict__ edst, int* __restrict__ counts)
{
  int idx = blockIdx.x * 256 + threadIdx.x;
  if (idx >= 2 * NE) return;
  int et = (idx >= NE) ? 1 : 0;
  atomicAdd(&counts[et * CELLS + edst[idx]], 1);
}

__global__ void scan1_kernel(const int* __restrict__ counts, int* __restrict__ S,
                             int* __restrict__ btot)
{
  __shared__ int sh[1024];
  const int t = threadIdx.x, b = blockIdx.x;
  const int i = b * 1024 + t;
  int v = counts[i];
  sh[t] = v;
  __syncthreads();
  int acc = v;
  for (int off = 1; off < 1024; off <<= 1) {
    int add = (t >= off) ? sh[t - off] : 0;
    __syncthreads();
    acc += add;
    sh[t] = acc;
    __syncthreads();
  }
  S[i] = acc - v;  // block-local exclusive
  if (t == 1023) btot[b] = acc;
}

__global__ void scan2_kernel(const int* __restrict__ btot, int* __restrict__ boffs,
                             int* __restrict__ S)
{
  __shared__ int sh[256];
  const int t = threadIdx.x;
  int v = (t < 192) ? btot[t] : 0;
  sh[t] = v;
  __syncthreads();
  int acc = v;
  for (int off = 1; off < 256; off <<= 1) {
    int add = (t >= off) ? sh[t - off] : 0;
    __syncthreads();
    acc += add;
    sh[t] = acc;
    __syncthreads();
  }
  if (t < 192) boffs[t] = acc - v;
  if (t == 0) S[2 * CELLS] = 2 * NE;
}

__global__ void scan3_kernel(int* __restrict__ S, const int* __restrict__ boffs)
{
  const int i = blockIdx.x * 1024 + threadIdx.x;
  S[i] += boffs[blockIdx.x];
}

__global__ void scatter_kernel(const int* __restrict__ esrc, const int* __restrict__ edst,
                               const int* __restrict__ S, int* __restrict__ fill,
                               int* __restrict__ ssrc, int* __restrict__ sdst)
{
  int idx = blockIdx.x * 256 + threadIdx.x;
  if (idx >= 2 * NE) return;
  int et = (idx >= NE) ? 1 : 0;
  int d = edst[idx];
  int pos = atomicAdd(&fill[et * CELLS + d], 1);
  int slot = S[et * CELLS + d] - et * NE + pos;  // et-local sorted slot
  sdst[et * NE + slot] = d;
  ssrc[et * NE + slot] = esrc[idx];
}

// bias + relu + pack-transpose into swizzled per-wave LDS A-tile (32 rows, pitch 128)
__device__ __forceinline__ void bias_relu_store(f32x4 (&acc)[2][8], const float* __restrict__ bl,
                                                u16* __restrict__ ab, int q, int c)
{
  float bias[8];
  #pragma unroll
  for (int j = 0; j < 8; ++j) bias[j] = bl[c * 8 + j];
  #pragma unroll
  for (int mt = 0; mt < 2; ++mt) {
    #pragma unroll
    for (int r = 0; r < 4; ++r) {
      const int rowl = mt * 16 + 4 * q + r;
      short8 t;
      #pragma unroll
      for (int nt = 0; nt < 8; ++nt) {
        float v = acc[mt][nt][r] + bias[nt];
        v = v > 0.f ? v : 0.f;
        t[nt] = (short)f2bf(v);
      }
      *(short8*)(ab + rowl * 128 + ((c ^ (rowl & 15)) << 3)) = t;
    }
  }
}

// ---------------- fused 4-layer edge MLP + sorted segmented-sum scatter ----------------
// block: 2 waves x 32 edges (dst-sorted), 16KB LDS -> 16 waves/CU; grid.y = edge type
// m layout ("epilogue order"): m[d][h*64 + l] = pi-slot (l>>2)*8 + 4h + (l&3)
__launch_bounds__(128, 4)
__global__ void msg_kernel(
    const u16* __restrict__ h,
    const int* __restrict__ ssrc, const int* __restrict__ sdst,
    const int* __restrict__ S,
    const u16* __restrict__ W0b, const u16* __restrict__ W1b,
    const u16* __restrict__ W2b, const u16* __restrict__ W3b,
    const float* __restrict__ bp,
    float* __restrict__ m0, float* __restrict__ m1)
{
  __shared__ u16 abuf[2][32 * 128];  // 8KB per wave, wave-private, XOR-swizzled
  const int et = blockIdx.y;
  const int tid = threadIdx.x;
  const int w = tid >> 6, lane = tid & 63, q = lane >> 4, c = lane & 15;
  const int ebase = blockIdx.x * 64 + w * 32;  // et-local sorted slot base for this wave
  const int* __restrict__ src = ssrc + et * NE;
  const int* __restrict__ dst = sdst + et * NE;
  const u16* __restrict__ Wl0 = W0b + et * 32768;
  const u16* __restrict__ Wl[3] = {W1b + et * 16384, W2b + et * 16384, W3b + et * 16384};
  float* __restrict__ msgs = (et == 0) ? m0 : m1;
  u16* ab = abuf[w];

  int rowS[2], rowD[2];
  #pragma unroll
  for (int mt = 0; mt < 2; ++mt) {
    int e = ebase + mt * 16 + c;
    if (e >= NE) e = NE - 1;
    rowS[mt] = src[e];
    rowD[mt] = dst[e];
  }

  // run structure for the segmented epilogue: only lanes 0..31 carry edges.
  // Cross-lane ops are unconditional (round-3 lesson: exec-masked source lanes
  // give undefined shuffle reads).
  const int eL = ebase + lane;
  const int dval = (lane < 32 && eL < NE) ? dst[eL] : -1;
  int rpS = 0, rpE = 0;
  if (dval >= 0) {
    rpS = S[et * CELLS + dval] - et * NE;
    rpE = S[et * CELLS + dval + 1] - et * NE;
  }
  const int dlagged = __shfl_up(dval, 1);          // all 64 lanes active
  const bool headp = (lane == 0) | (dval != dlagged);
  const unsigned long long tails =
      (((__ballot(headp) & 0xFFFFFFFFull) >> 1) | (1ull << 31));
  const unsigned long long intmask = __ballot(dval >= 0 && rpS >= ebase && rpE <= ebase + 32);

  const f32x4 zf = {0.f, 0.f, 0.f, 0.f};
  f32x4 acc[2][8];
  #pragma unroll
  for (int mt = 0; mt < 2; ++mt)
    #pragma unroll
    for (int nt = 0; nt < 8; ++nt) acc[mt][nt] = zf;

  // layer 0: K=256 = [h[src] | h[dst]], A gathered straight from global h (16B/lane)
  #pragma unroll
  for (int ks = 0; ks < 8; ++ks) {
    const int kq = ks * 32 + q * 8;
    short8 a[2], b[8];
    #pragma unroll
    for (int mt = 0; mt < 2; ++mt) {
      int row = (ks < 4) ? rowS[mt] : rowD[mt];
      a[mt] = *(const short8*)(h + row * HID + (kq & 127));
    }
    #pragma unroll
    for (int nt = 0; nt < 8; ++nt)
      b[nt] = *(const short8*)(Wl0 + (nt * 16 + c) * 256 + kq);
    #pragma unroll
    for (int mt = 0; mt < 2; ++mt)
      #pragma unroll
      for (int nt = 0; nt < 8; ++nt)
        acc[mt][nt] = __builtin_amdgcn_mfma_f32_16x16x32_bf16(a[mt], b[nt], acc[mt][nt], 0, 0, 0);
  }
  bias_relu_store(acc, bp + et * 128, ab, q, c);

  // layers 1..3 (wave-private LDS round-trip; in-order DS => no barriers)
  #pragma unroll
  for (int l = 0; l < 3; ++l) {
    #pragma unroll
    for (int mt = 0; mt < 2; ++mt)
      #pragma unroll
      for (int nt = 0; nt < 8; ++nt) acc[mt][nt] = zf;
    #pragma unroll
    for (int ks = 0; ks < 4; ++ks) {
      const int kq = ks * 32 + q * 8;
      const int blk = ks * 4 + q;
      short8 a[2], b[8];
      #pragma unroll
      for (int mt = 0; mt < 2; ++mt) {
        const int row = mt * 16 + c;
        a[mt] = *(const short8*)(ab + row * 128 + ((blk ^ c) << 3));
      }
      #pragma unroll
      for (int nt = 0; nt < 8; ++nt)
        b[nt] = *(const short8*)(Wl[l] + (nt * 16 + c) * 128 + kq);
      #pragma unroll
      for (int mt = 0; mt < 2; ++mt)
        #pragma unroll
        for (int nt = 0; nt < 8; ++nt)
          acc[mt][nt] = __builtin_amdgcn_mfma_f32_16x16x32_bf16(a[mt], b[nt], acc[mt][nt], 0, 0, 0);
    }
    if (l < 2) bias_relu_store(acc, bp + (l + 1) * 256 + et * 128, ab, q, c);
  }

  // layer-3 epilogue: +bias, LDS fp32 transpose (two 64-feature passes over 32 rows),
  // unrolled segmented sum over sorted dst; plain contiguous 256B store for
  // wave-interior dsts, atomic at wave borders.
  float bias[8];
  #pragma unroll
  for (int j = 0; j < 8; ++j) bias[j] = bp[3 * 256 + et * 128 + c * 8 + j];

  float* fab = (float*)ab;  // 32 rows x 64 feature-slots fp32 (8KB, wave-private)
  #pragma unroll
  for (int half = 0; half < 2; ++half) {
    #pragma unroll
    for (int mt = 0; mt < 2; ++mt) {
      #pragma unroll
      for (int r = 0; r < 4; ++r) {
        const int row = mt * 16 + 4 * q + r;
        f32x4 t;
        #pragma unroll
        for (int nti = 0; nti < 4; ++nti)
          t[nti] = acc[mt][half * 4 + nti][r] + bias[half * 4 + nti];
        *(f32x4*)(fab + row * 64 + c * 4) = t;
      }
    }
    // column `lane` holds pi-slot (lane>>2)*8 + half*4 + (lane&3) == position half*64+lane
    float run = 0.f;
    #pragma unroll
    for (int j = 0; j < 32; ++j) {
      run += fab[j * 64 + lane];
      if ((tails >> j) & 1) {  // wave-uniform flush at run tail
        const int d = __builtin_amdgcn_readlane(dval, j);
        if (d >= 0) {
          float* mp = msgs + (size_t)d * HID + half * 64 + lane;
          if ((intmask >> j) & 1) *mp = run;
          else atomicAdd(mp, run);
        }
        run = 0.f;
      }
    }
  }
}

// ---------------- fused LSTM: gates GEMM (K=512) + activations + score ----------------
// block: 4 waves, 32 cells, full 512 gates (wave w = gate quarter w); 32KB LDS
__launch_bounds__(256, 4)
__global__ void lstm_kernel(
    const int step,
    const u16* __restrict__ xb, const float* __restrict__ mm0, const float* __restrict__ mm1,
    u16* __restrict__ h, float* __restrict__ rc,
    const u16* __restrict__ Wcb, const float* __restrict__ swp,
    float* __restrict__ out)
{
  __shared__ u16 at[32 * 512];  // 32KB swizzled: A-tile, then gates exchange, then score
  const int tid = threadIdx.x;
  const int cb = blockIdx.x * 32;

  // stage A = [x | m0 | m1 | rh] as bf16 (rh = 0 at step 0); m is in "epilogue order"
  for (int base = tid * 8; base < 32 * 512; base += 2048) {
    const int cl = base >> 9, s = base & 511;
    const int cell = cb + cl;
    short8 t;
    if (s < 128) {
      t = *(const short8*)(xb + cell * 128 + s);
    } else if (s < 384) {
      const float* mp = (s < 256 ? mm0 : mm1) + cell * 128;
      const int cc = (s & 127) >> 3;
      f32x4 lo = *(const f32x4*)(mp + cc * 4);        // pi-slots 8cc+0..3
      f32x4 hi = *(const f32x4*)(mp + 64 + cc * 4);   // pi-slots 8cc+4..7
      #pragma unroll
      for (int j = 0; j < 4; ++j) { t[j] = (short)f2bf(lo[j]); t[4 + j] = (short)f2bf(hi[j]); }
    } else if (step == 0) {
      #pragma unroll
      for (int j = 0; j < 8; ++j) t[j] = 0;
    } else {
      t = *(const short8*)(h + cell * 128 + (s & 127));
    }
    const int blk = s >> 3;
    const int blks = (blk & 48) | ((blk ^ cl) & 15);
    *(short8*)(at + cl * 512 + blks * 8) = t;
  }
  __syncthreads();

  const int w = tid >> 6, lane = tid & 63, q = lane >> 4, c = lane & 15;
  const f32x4 zf = {0.f, 0.f, 0.f, 0.f};
  f32x4 acc[2][8];
  #pragma unroll
  for (int mt = 0; mt < 2; ++mt)
    #pragma unroll
    for (int nt = 0; nt < 8; ++nt) acc[mt][nt] = zf;

  #pragma unroll
  for (int ks = 0; ks < 16; ++ks) {
    const int kq = ks * 32 + q * 8;
    const int blk = (kq >> 3);  // 0..63
    short8 a[2], b[8];
    #pragma unroll
    for (int mt = 0; mt < 2; ++mt) {
      const int row = mt * 16 + c;
      const int blks = (blk & 48) | ((blk ^ c) & 15);
      a[mt] = *(const short8*)(at + row * 512 + blks * 8);
    }
    #pragma unroll
    for (int nt = 0; nt < 8; ++nt)
      b[nt] = *(const short8*)(Wcb + (w * 128 + nt * 16 + c) * 512 + kq);
    #pragma unroll
    for (int mt = 0; mt < 2; ++mt)
      #pragma unroll
      for (int nt = 0; nt < 8; ++nt)
        acc[mt][nt] = __builtin_amdgcn_mfma_f32_16x16x32_bf16(a[mt], b[nt], acc[mt][nt], 0, 0, 0);
  }
  __syncthreads();

  // exchange gates through LDS (bf16, same swizzle)
  #pragma unroll
  for (int mt = 0; mt < 2; ++mt) {
    #pragma unroll
    for (int r = 0; r < 4; ++r) {
      const int rowl = mt * 16 + 4 * q + r;
      short8 t;
      #pragma unroll
      for (int nt = 0; nt < 8; ++nt) t[nt] = (short)f2bf(acc[mt][nt][r]);
      const int blks = (w << 4) | ((c ^ (rowl & 15)) & 15);
      *(short8*)(at + rowl * 512 + blks * 8) = t;
    }
  }
  __syncthreads();

  // epilogue: lane (w,q,c) -> cell (w&1)*16+c, 16 feats at q*32 + (w>>1)*16
  const int cl = ((w & 1) << 4) + c;
  const int fhalf = w >> 1;
  const int cell = cb + cl;
  const int fbase = q * 32 + fhalf * 16;
  float* rcp = rc + cell * 128 + fbase;
  u16* hp = h + cell * 128 + fbase;
  const float* swq = swp + fbase;
  float lsum = 0.f;
  #pragma unroll
  for (int jj = 0; jj < 16; jj += 8) {
    const int bq = q * 4 + fhalf * 2 + (jj >> 3);  // within-quarter block 0..15
    const int bx = (bq ^ cl) & 15;
    short8 iv = *(const short8*)(at + cl * 512 + ((0 << 4) | bx) * 8);
    short8 fv = *(const short8*)(at + cl * 512 + ((1 << 4) | bx) * 8);
    short8 gv = *(const short8*)(at + cl * 512 + ((2 << 4) | bx) * 8);
    short8 ov = *(const short8*)(at + cl * 512 + ((3 << 4) | bx) * 8);
    short8 nh8;
    #pragma unroll
    for (int j = 0; j < 8; ++j) {
      float ig = sigm(bf2f((u16)iv[j]));
      float fg = sigm(bf2f((u16)fv[j]));
      float gg = tanha(bf2f((u16)gv[j]));
      float og = sigm(bf2f((u16)ov[j]));
      float c0 = rcp[jj + j];
      float nc = fg * c0 + ig * gg;
      float nhv = og * tanha(nc);
      rcp[jj + j] = nc;
      nh8[j] = (short)f2bf(nhv);
      lsum += nhv * swq[jj + j];
    }
    *(short8*)(hp + jj) = nh8;
  }
  // reduce over q within the wave (lanes differing in bits 4..5 share a cell)
  lsum += __shfl_xor(lsum, 16);
  lsum += __shfl_xor(lsum, 32);
  // cross-wave combine (fhalf 0 vs 1) via LDS reuse
  __syncthreads();
  float* sc = (float*)at;  // 64 floats
  if (q == 0) sc[fhalf * 32 + cl] = lsum;
  __syncthreads();
  if (tid < 32) out[step * CELLS + cb + tid] = sc[tid] + sc[32 + tid];
}

extern "C" void kernel_launch(void* const* d_in, const int* in_sizes, int n_in,
                              void* d_out, int out_size, void* d_ws, size_t ws_size,
                              hipStream_t stream)
{
  const int* q      = (const int*)d_in[0];
  const int* esrc   = (const int*)d_in[1];
  const int* edst   = (const int*)d_in[2];
  const float* embed= (const float*)d_in[3];
  const float* W0   = (const float*)d_in[4];
  const float* b0   = (const float*)d_in[5];
  const float* W1   = (const float*)d_in[6];
  const float* b1   = (const float*)d_in[7];
  const float* W2   = (const float*)d_in[8];
  const float* b2   = (const float*)d_in[9];
  const float* W3   = (const float*)d_in[10];
  const float* b3   = (const float*)d_in[11];
  const float* Wih  = (const float*)d_in[12];
  const float* Whh  = (const float*)d_in[13];
  const float* sw   = (const float*)d_in[14];

  char* ws = (char*)d_ws;
  size_t off = 0;
  auto alloc = [&](size_t bytes) {
    void* p = ws + off;
    off += (bytes + 255) & ~(size_t)255;
    return p;
  };
  u16*   h    = (u16*)  alloc((size_t)CELLS * HID * 2);
  u16*   xb   = (u16*)  alloc((size_t)CELLS * HID * 2);
  float* rc   = (float*)alloc((size_t)CELLS * HID * 4);
  float* m0   = (float*)alloc((size_t)CELLS * HID * 4);
  float* m1   = (float*)alloc((size_t)CELLS * HID * 4);
  u16*   W0b  = (u16*)  alloc(2 * 128 * 256 * 2);
  u16*   W1b  = (u16*)  alloc(2 * 128 * 128 * 2);
  u16*   W2b  = (u16*)  alloc(2 * 128 * 128 * 2);
  u16*   W3b  = (u16*)  alloc(2 * 128 * 128 * 2);
  u16*   Wcb  = (u16*)  alloc(512 * 512 * 2);
  float* bp   = (float*)alloc(4 * 256 * 4);
  u16*   embp = (u16*)  alloc(384 * 2);
  float* swp  = (float*)alloc(128 * 4);
  // sort workspace
  int*   counts = (int*)alloc((size_t)2 * CELLS * 4);
  int*   Sarr   = (int*)alloc(((size_t)2 * CELLS + 1) * 4);
  int*   fill   = (int*)alloc((size_t)2 * CELLS * 4);
  int*   btot   = (int*)alloc(192 * 4);
  int*   boffs  = (int*)alloc(192 * 4);
  int*   ssrc   = (int*)alloc((size_t)2 * NE * 4);
  int*   sdst   = (int*)alloc((size_t)2 * NE * 4);

  prep_kernel<<<1670, 256, 0, stream>>>(W0, W1, W2, W3, b0, b1, b2, b3, Wih, Whh, embed, sw,
                                        W0b, W1b, W2b, W3b, Wcb, bp, embp, swp);
  init_kernel<<<(CELLS * HID) / 256, 256, 0, stream>>>(q, embp, xb, h, rc);

  // dst-sort both edge types
  hipMemsetAsync(counts, 0, (size_t)2 * CELLS * 4, stream);
  hipMemsetAsync(fill, 0, (size_t)2 * CELLS * 4, stream);
  hist_kernel<<<(2 * NE + 255) / 256, 256, 0, stream>>>(edst, counts);
  scan1_kernel<<<192, 1024, 0, stream>>>(counts, Sarr, btot);
  scan2_kernel<<<1, 256, 0, stream>>>(btot, boffs, Sarr);
  scan3_kernel<<<192, 1024, 0, stream>>>(Sarr, boffs);
  scatter_kernel<<<(2 * NE + 255) / 256, 256, 0, stream>>>(esrc, edst, Sarr, fill, ssrc, sdst);

  for (int step = 0; step < NSTEPS; ++step) {
    hipMemsetAsync(m0, 0, (size_t)CELLS * HID * 4, stream);
    hipMemsetAsync(m1, 0, (size_t)CELLS * HID * 4, stream);
    msg_kernel<<<dim3((NE + 63) / 64, 2), 128, 0, stream>>>(h, ssrc, sdst, Sarr,
                                                            W0b, W1b, W2b, W3b, bp, m0, m1);
    lstm_kernel<<<CELLS / 32, 256, 0, stream>>>(step, xb, m0, m1, h, rc, Wcb, swp, (float*)d_out);
  }
}

// Round 6
// 1070.920 us; speedup vs baseline: 1.4345x; 1.4345x over previous
//
#include <hip/hip_runtime.h>

#define HID 128
#define CELLS 98304
#define NE 250000
#define NSTEPS 2

typedef __attribute__((ext_vector_type(8))) short short8;
typedef __attribute__((ext_vector_type(4))) float f32x4;
typedef unsigned short u16;

// pi permutation: stored slot s holds natural feature perm(s)
__device__ __forceinline__ int permf(int s) { return ((s & 7) << 4) | (s >> 3); }

__device__ __forceinline__ u16 f2bf(float f) {
  unsigned int u = __builtin_bit_cast(unsigned int, f);
  u += 0x7fffu + ((u >> 16) & 1u);
  return (u16)(u >> 16);
}
__device__ __forceinline__ float bf2f(u16 s) {
  unsigned int u = ((unsigned int)s) << 16;
  return __builtin_bit_cast(float, u);
}
__device__ __forceinline__ float sigm(float x) { return 1.f / (1.f + __expf(-x)); }
__device__ __forceinline__ float tanha(float x) { return 1.f - 2.f / (__expf(2.f * x) + 1.f); }

// ---------------- prep: bf16-convert + pi-permute all weights ----------------
__global__ void prep_kernel(
    const float* __restrict__ W0, const float* __restrict__ W1,
    const float* __restrict__ W2, const float* __restrict__ W3,
    const float* __restrict__ b0, const float* __restrict__ b1,
    const float* __restrict__ b2, const float* __restrict__ b3,
    const float* __restrict__ Wih, const float* __restrict__ Whh,
    const float* __restrict__ embed, const float* __restrict__ sw,
    u16* __restrict__ W0b, u16* __restrict__ W1b,
    u16* __restrict__ W2b, u16* __restrict__ W3b,
    u16* __restrict__ Wcb, float* __restrict__ bp,
    u16* __restrict__ embp, float* __restrict__ swp)
{
  int idx = blockIdx.x * 256 + threadIdx.x;
  if (idx < 65536) {  // W0b [et][n][s], s in [0,256): k_nat = perm on each 128-half
    int s = idx & 255, n = (idx >> 8) & 127, et = idx >> 15;
    int k = (s < 128) ? permf(s) : (128 + permf(s & 127));
    W0b[idx] = f2bf(W0[(et * 128 + n) * 256 + k]);
    return;
  }
  idx -= 65536;
  if (idx < 98304) {  // W1b/W2b/W3b [et][n][s]
    int which = idx >> 15, r = idx & 32767;
    int s = r & 127, n = (r >> 7) & 127, et = r >> 14;
    const float* W = which == 0 ? W1 : (which == 1 ? W2 : W3);
    u16* Wb = which == 0 ? W1b : (which == 1 ? W2b : W3b);
    Wb[r] = f2bf(W[(et * 128 + n) * 128 + permf(s)]);
    return;
  }
  idx -= 98304;
  if (idx < 262144) {  // Wcat [n=512][s=512] = [Wih(x|m0|m1) | Whh], per-128-block perm on K
    int s = idx & 511, n = idx >> 9;
    int blk = s >> 7, s7 = s & 127;
    float v = (blk < 3) ? Wih[n * 384 + blk * 128 + permf(s7)] : Whh[n * 128 + permf(s7)];
    Wcb[idx] = f2bf(v);
    return;
  }
  idx -= 262144;
  if (idx < 1024) {  // biases [layer 0..3][et][s] pi-order
    int l = idx >> 8, r = idx & 255;
    int et = r >> 7, s = r & 127;
    const float* b = l == 0 ? b0 : (l == 1 ? b1 : (l == 2 ? b2 : b3));
    bp[idx] = b[et * 128 + permf(s)];
    return;
  }
  idx -= 1024;
  if (idx < 384) {  // embed pi-order bf16
    int v = idx >> 7, s = idx & 127;
    embp[idx] = f2bf(embed[v * 128 + permf(s)]);
    return;
  }
  idx -= 384;
  if (idx < 128) swp[idx] = sw[permf(idx)];
}

// ---------------- init: x = embed[q] (pi, bf16), h = x, rc = 0 ----------------
__global__ void init_kernel(const int* __restrict__ q, const u16* __restrict__ embp,
                            u16* __restrict__ xb, u16* __restrict__ h, float* __restrict__ rc)
{
  int idx = blockIdx.x * 256 + threadIdx.x;
  int c = idx >> 7, s = idx & 127;
  u16 v = embp[q[c] * 128 + s];
  xb[idx] = v;
  h[idx] = v;
  rc[idx] = 0.f;
}

// ---------------- dst-sort pipeline: hist -> scan (2-level) -> scatter ----------------
__global__ void hist_kernel(const int* __restrict__ edst, int* __restrict__ counts)
{
  int idx = blockIdx.x * 256 + threadIdx.x;
  if (idx >= 2 * NE) return;
  int et = (idx >= NE) ? 1 : 0;
  atomicAdd(&counts[et * CELLS + edst[idx]], 1);
}

__global__ void scan1_kernel(const int* __restrict__ counts, int* __restrict__ S,
                             int* __restrict__ btot)
{
  __shared__ int sh[1024];
  const int t = threadIdx.x, b = blockIdx.x;
  const int i = b * 1024 + t;
  int v = counts[i];
  sh[t] = v;
  __syncthreads();
  int acc = v;
  for (int off = 1; off < 1024; off <<= 1) {
    int add = (t >= off) ? sh[t - off] : 0;
    __syncthreads();
    acc += add;
    sh[t] = acc;
    __syncthreads();
  }
  S[i] = acc - v;  // block-local exclusive
  if (t == 1023) btot[b] = acc;
}

__global__ void scan2_kernel(const int* __restrict__ btot, int* __restrict__ boffs,
                             int* __restrict__ S)
{
  __shared__ int sh[256];
  const int t = threadIdx.x;
  int v = (t < 192) ? btot[t] : 0;
  sh[t] = v;
  __syncthreads();
  int acc = v;
  for (int off = 1; off < 256; off <<= 1) {
    int add = (t >= off) ? sh[t - off] : 0;
    __syncthreads();
    acc += add;
    sh[t] = acc;
    __syncthreads();
  }
  if (t < 192) boffs[t] = acc - v;
  if (t == 0) S[2 * CELLS] = 2 * NE;
}

__global__ void scan3_kernel(int* __restrict__ S, const int* __restrict__ boffs)
{
  const int i = blockIdx.x * 1024 + threadIdx.x;
  S[i] += boffs[blockIdx.x];
}

__global__ void scatter_kernel(const int* __restrict__ esrc, const int* __restrict__ edst,
                               const int* __restrict__ S, int* __restrict__ fill,
                               int* __restrict__ ssrc, int* __restrict__ sdst)
{
  int idx = blockIdx.x * 256 + threadIdx.x;
  if (idx >= 2 * NE) return;
  int et = (idx >= NE) ? 1 : 0;
  int d = edst[idx];
  int pos = atomicAdd(&fill[et * CELLS + d], 1);
  int slot = S[et * CELLS + d] - et * NE + pos;  // et-local sorted slot
  sdst[et * NE + slot] = d;
  ssrc[et * NE + slot] = esrc[idx];
}

// bias + relu + pack-transpose into swizzled per-wave LDS A-tile (pitch 128, 8-col XOR swizzle)
__device__ __forceinline__ void bias_relu_store(f32x4 (&acc)[4][8], const float* __restrict__ bl,
                                                u16* __restrict__ ab, int q, int c)
{
  float bias[8];
  #pragma unroll
  for (int j = 0; j < 8; ++j) bias[j] = bl[c * 8 + j];
  #pragma unroll
  for (int mt = 0; mt < 4; ++mt) {
    #pragma unroll
    for (int r = 0; r < 4; ++r) {
      const int rowl = mt * 16 + 4 * q + r;
      short8 t;
      #pragma unroll
      for (int nt = 0; nt < 8; ++nt) {
        float v = acc[mt][nt][r] + bias[nt];
        v = v > 0.f ? v : 0.f;
        t[nt] = (short)f2bf(v);
      }
      *(short8*)(ab + rowl * 128 + ((c ^ (rowl & 15)) << 3)) = t;
    }
  }
}

// ---------------- fused 4-layer edge MLP + sorted segmented-sum scatter ----------------
// block: 2 waves x 64 edges (dst-sorted), 32KB LDS; grid.y = edge type  [round-4 winner]
// m layout ("epilogue order"): m[d][h*64 + l] = pi-slot (l>>2)*8 + 4h + (l&3)
__launch_bounds__(128, 2)
__global__ void msg_kernel(
    const u16* __restrict__ h,
    const int* __restrict__ ssrc, const int* __restrict__ sdst,
    const int* __restrict__ S,
    const u16* __restrict__ W0b, const u16* __restrict__ W1b,
    const u16* __restrict__ W2b, const u16* __restrict__ W3b,
    const float* __restrict__ bp,
    float* __restrict__ m0, float* __restrict__ m1)
{
  __shared__ u16 abuf[2][64 * 128];  // 32KB, per-wave private, XOR-swizzled
  const int et = blockIdx.y;
  const int tid = threadIdx.x;
  const int w = tid >> 6, lane = tid & 63, q = lane >> 4, c = lane & 15;
  const int ebase = blockIdx.x * 128 + w * 64;  // et-local sorted slot base for this wave
  const int* __restrict__ src = ssrc + et * NE;
  const int* __restrict__ dst = sdst + et * NE;
  const u16* __restrict__ Wl0 = W0b + et * 32768;
  const u16* __restrict__ Wl[3] = {W1b + et * 16384, W2b + et * 16384, W3b + et * 16384};
  float* __restrict__ msgs = (et == 0) ? m0 : m1;
  u16* ab = abuf[w];

  int rowS[4], rowD[4];
  #pragma unroll
  for (int mt = 0; mt < 4; ++mt) {
    int e = ebase + mt * 16 + c;
    if (e >= NE) e = NE - 1;
    rowS[mt] = src[e];
    rowD[mt] = dst[e];
  }

  // run structure for the segmented epilogue (computed once, wave-uniform masks).
  // Cross-lane ops unconditional (round-3 lesson: exec-masked source lanes are undefined).
  const int eL = ebase + lane;
  const int dval = (eL < NE) ? dst[eL] : -1;
  int rpS = 0, rpE = 0;
  if (dval >= 0) {
    rpS = S[et * CELLS + dval] - et * NE;
    rpE = S[et * CELLS + dval + 1] - et * NE;
  }
  const int dlagged = __shfl_up(dval, 1);          // all 64 lanes active
  const bool headp = (lane == 0) | (dval != dlagged);  // bitwise | : no control flow
  const unsigned long long tails = (__ballot(headp) >> 1) | (1ull << 63);
  const unsigned long long intmask = __ballot(dval >= 0 && rpS >= ebase && rpE <= ebase + 64);

  const f32x4 zf = {0.f, 0.f, 0.f, 0.f};
  f32x4 acc[4][8];
  #pragma unroll
  for (int mt = 0; mt < 4; ++mt)
    #pragma unroll
    for (int nt = 0; nt < 8; ++nt) acc[mt][nt] = zf;

  // layer 0: K=256 = [h[src] | h[dst]], A gathered straight from global h (16B/lane)
  #pragma unroll
  for (int ks = 0; ks < 8; ++ks) {
    const int kq = ks * 32 + q * 8;
    short8 a[4], b[8];
    #pragma unroll
    for (int mt = 0; mt < 4; ++mt) {
      int row = (ks < 4) ? rowS[mt] : rowD[mt];
      a[mt] = *(const short8*)(h + row * HID + (kq & 127));
    }
    #pragma unroll
    for (int nt = 0; nt < 8; ++nt)
      b[nt] = *(const short8*)(Wl0 + (nt * 16 + c) * 256 + kq);
    #pragma unroll
    for (int mt = 0; mt < 4; ++mt)
      #pragma unroll
      for (int nt = 0; nt < 8; ++nt)
        acc[mt][nt] = __builtin_amdgcn_mfma_f32_16x16x32_bf16(a[mt], b[nt], acc[mt][nt], 0, 0, 0);
  }
  bias_relu_store(acc, bp + et * 128, ab, q, c);

  // layers 1..3 (wave-private LDS round-trip; in-order DS => no barriers)
  #pragma unroll
  for (int l = 0; l < 3; ++l) {
    #pragma unroll
    for (int mt = 0; mt < 4; ++mt)
      #pragma unroll
      for (int nt = 0; nt < 8; ++nt) acc[mt][nt] = zf;
    #pragma unroll
    for (int ks = 0; ks < 4; ++ks) {
      const int kq = ks * 32 + q * 8;
      const int blk = ks * 4 + q;
      short8 a[4], b[8];
      #pragma unroll
      for (int mt = 0; mt < 4; ++mt) {
        const int row = mt * 16 + c;
        a[mt] = *(const short8*)(ab + row * 128 + ((blk ^ c) << 3));
      }
      #pragma unroll
      for (int nt = 0; nt < 8; ++nt)
        b[nt] = *(const short8*)(Wl[l] + (nt * 16 + c) * 128 + kq);
      #pragma unroll
      for (int mt = 0; mt < 4; ++mt)
        #pragma unroll
        for (int nt = 0; nt < 8; ++nt)
          acc[mt][nt] = __builtin_amdgcn_mfma_f32_16x16x32_bf16(a[mt], b[nt], acc[mt][nt], 0, 0, 0);
    }
    if (l < 2) bias_relu_store(acc, bp + (l + 1) * 256 + et * 128, ab, q, c);
  }

  // layer-3 epilogue: +bias, LDS fp32 transpose (two 64-feature passes), unrolled
  // segmented sum over sorted dst; plain contiguous 256B store for wave-interior
  // dsts, atomic at wave borders.
  float bias[8];
  #pragma unroll
  for (int j = 0; j < 8; ++j) bias[j] = bp[3 * 256 + et * 128 + c * 8 + j];

  float* fab = (float*)ab;  // 64 rows x 64 feature-slots fp32 (16KB, wave-private)
  #pragma unroll
  for (int half = 0; half < 2; ++half) {
    #pragma unroll
    for (int mt = 0; mt < 4; ++mt) {
      #pragma unroll
      for (int r = 0; r < 4; ++r) {
        const int row = mt * 16 + 4 * q + r;
        f32x4 t;
        #pragma unroll
        for (int nti = 0; nti < 4; ++nti)
          t[nti] = acc[mt][half * 4 + nti][r] + bias[half * 4 + nti];
        *(f32x4*)(fab + row * 64 + c * 4) = t;
      }
    }
    // column `lane` holds pi-slot (lane>>2)*8 + half*4 + (lane&3) == position half*64+lane
    float run = 0.f;
    #pragma unroll
    for (int j = 0; j < 64; ++j) {
      run += fab[j * 64 + lane];
      if ((tails >> j) & 1) {  // wave-uniform flush at run tail
        const int d = __builtin_amdgcn_readlane(dval, j);
        if (d >= 0) {
          float* mp = msgs + (size_t)d * HID + half * 64 + lane;
          if ((intmask >> j) & 1) *mp = run;
          else atomicAdd(mp, run);
        }
        run = 0.f;
      }
    }
  }
}

// ---------------- fused LSTM: gates GEMM (K=512) + activations + score ----------------
// block: 8 waves, 64 cells; wave (qt = w&3, mh = w>>2): gate quarter qt, cell half mh.
// acc[2][8] = 64 AGPR + ~60 VGPR -> 4 waves/SIMD; 64KB LDS -> 2 blocks/CU = 16 waves/CU.
__launch_bounds__(512, 4)
__global__ void lstm_kernel(
    const int step,
    const u16* __restrict__ xb, const float* __restrict__ mm0, const float* __restrict__ mm1,
    u16* __restrict__ h, float* __restrict__ rc,
    const u16* __restrict__ Wcb, const float* __restrict__ swp,
    float* __restrict__ out)
{
  __shared__ u16 at[64 * 512];  // 64KB swizzled: A-tile, then reused for gates exchange
  const int tid = threadIdx.x;
  const int cb = blockIdx.x * 64;

  // stage A = [x | m0 | m1 | rh] as bf16 (rh = 0 at step 0); m is in "epilogue order"
  for (int base = tid * 8; base < 64 * 512; base += 4096) {
    const int cl = base >> 9, s = base & 511;
    const int cell = cb + cl;
    short8 t;
    if (s < 128) {
      t = *(const short8*)(xb + cell * 128 + s);
    } else if (s < 384) {
      const float* mp = (s < 256 ? mm0 : mm1) + cell * 128;
      const int cc = (s & 127) >> 3;
      f32x4 lo = *(const f32x4*)(mp + cc * 4);        // pi-slots 8cc+0..3
      f32x4 hi = *(const f32x4*)(mp + 64 + cc * 4);   // pi-slots 8cc+4..7
      #pragma unroll
      for (int j = 0; j < 4; ++j) { t[j] = (short)f2bf(lo[j]); t[4 + j] = (short)f2bf(hi[j]); }
    } else if (step == 0) {
      #pragma unroll
      for (int j = 0; j < 8; ++j) t[j] = 0;
    } else {
      t = *(const short8*)(h + cell * 128 + (s & 127));
    }
    const int blk = s >> 3;
    const int blks = (blk & 48) | ((blk ^ cl) & 15);
    *(short8*)(at + cl * 512 + blks * 8) = t;
  }
  __syncthreads();

  const int w = tid >> 6, lane = tid & 63, q = lane >> 4, c = lane & 15;
  const int qt = w & 3, mh = w >> 2;
  const f32x4 zf = {0.f, 0.f, 0.f, 0.f};
  f32x4 acc[2][8];
  #pragma unroll
  for (int mt = 0; mt < 2; ++mt)
    #pragma unroll
    for (int nt = 0; nt < 8; ++nt) acc[mt][nt] = zf;

  #pragma unroll
  for (int ks = 0; ks < 16; ++ks) {
    const int kq = ks * 32 + q * 8;
    const int blk = (kq >> 3);  // 0..63
    short8 a[2];
    #pragma unroll
    for (int mt = 0; mt < 2; ++mt) {
      const int row = mh * 32 + mt * 16 + c;
      const int blks = (blk & 48) | ((blk ^ c) & 15);
      a[mt] = *(const short8*)(at + row * 512 + blks * 8);
    }
    #pragma unroll
    for (int g4 = 0; g4 < 2; ++g4) {  // B in groups of 4 to cap VGPR pressure
      short8 b[4];
      #pragma unroll
      for (int n4 = 0; n4 < 4; ++n4)
        b[n4] = *(const short8*)(Wcb + (qt * 128 + (g4 * 4 + n4) * 16 + c) * 512 + kq);
      #pragma unroll
      for (int mt = 0; mt < 2; ++mt)
        #pragma unroll
        for (int n4 = 0; n4 < 4; ++n4)
          acc[mt][g4 * 4 + n4] =
              __builtin_amdgcn_mfma_f32_16x16x32_bf16(a[mt], b[n4], acc[mt][g4 * 4 + n4], 0, 0, 0);
    }
  }
  __syncthreads();

  // exchange gates through LDS (bf16, same swizzle family)
  #pragma unroll
  for (int mt = 0; mt < 2; ++mt) {
    #pragma unroll
    for (int r = 0; r < 4; ++r) {
      const int rowl = mh * 32 + mt * 16 + 4 * q + r;
      short8 t;
      #pragma unroll
      for (int nt = 0; nt < 8; ++nt) t[nt] = (short)f2bf(acc[mt][nt][r]);
      const int blks = (qt << 4) | ((c ^ (rowl & 15)) & 15);
      *(short8*)(at + rowl * 512 + blks * 8) = t;
    }
  }
  __syncthreads();

  // epilogue: thread -> (cell cl = tid>>3, 16-feature chunk = tid&7)
  // element j of gate-block bq is gate column j*16+bq == permf(bq*8+j):
  // slot = chunk*16 + half2*8 + j, matching pi-ordered rc/h/swp.
  const int cl = tid >> 3, chunk = tid & 7;
  const int cell = cb + cl;
  float* rcp = rc + cell * 128 + chunk * 16;
  u16* hp = h + cell * 128 + chunk * 16;
  const float* swq = swp + chunk * 16;
  float lsum = 0.f;
  #pragma unroll
  for (int half2 = 0; half2 < 2; ++half2) {
    const int bq = chunk * 2 + half2;
    const int bx = (bq ^ (cl & 15)) & 15;
    short8 iv = *(const short8*)(at + cl * 512 + ((0 << 4) | bx) * 8);
    short8 fv = *(const short8*)(at + cl * 512 + ((1 << 4) | bx) * 8);
    short8 gv = *(const short8*)(at + cl * 512 + ((2 << 4) | bx) * 8);
    short8 ov = *(const short8*)(at + cl * 512 + ((3 << 4) | bx) * 8);
    short8 nh8;
    #pragma unroll
    for (int j = 0; j < 8; ++j) {
      float ig = sigm(bf2f((u16)iv[j]));
      float fg = sigm(bf2f((u16)fv[j]));
      float gg = tanha(bf2f((u16)gv[j]));
      float og = sigm(bf2f((u16)ov[j]));
      float c0 = rcp[half2 * 8 + j];
      float nc = fg * c0 + ig * gg;
      float nhv = og * tanha(nc);
      rcp[half2 * 8 + j] = nc;
      nh8[j] = (short)f2bf(nhv);
      lsum += nhv * swq[half2 * 8 + j];
    }
    *(short8*)(hp + half2 * 8) = nh8;
  }
  lsum += __shfl_xor(lsum, 1);
  lsum += __shfl_xor(lsum, 2);
  lsum += __shfl_xor(lsum, 4);
  if (chunk == 0) out[step * CELLS + cell] = lsum;
}

extern "C" void kernel_launch(void* const* d_in, const int* in_sizes, int n_in,
                              void* d_out, int out_size, void* d_ws, size_t ws_size,
                              hipStream_t stream)
{
  const int* q      = (const int*)d_in[0];
  const int* esrc   = (const int*)d_in[1];
  const int* edst   = (const int*)d_in[2];
  const float* embed= (const float*)d_in[3];
  const float* W0   = (const float*)d_in[4];
  const float* b0   = (const float*)d_in[5];
  const float* W1   = (const float*)d_in[6];
  const float* b1   = (const float*)d_in[7];
  const float* W2   = (const float*)d_in[8];
  const float* b2   = (const float*)d_in[9];
  const float* W3   = (const float*)d_in[10];
  const float* b3   = (const float*)d_in[11];
  const float* Wih  = (const float*)d_in[12];
  const float* Whh  = (const float*)d_in[13];
  const float* sw   = (const float*)d_in[14];

  char* ws = (char*)d_ws;
  size_t off = 0;
  auto alloc = [&](size_t bytes) {
    void* p = ws + off;
    off += (bytes + 255) & ~(size_t)255;
    return p;
  };
  u16*   h    = (u16*)  alloc((size_t)CELLS * HID * 2);
  u16*   xb   = (u16*)  alloc((size_t)CELLS * HID * 2);
  float* rc   = (float*)alloc((size_t)CELLS * HID * 4);
  float* m0   = (float*)alloc((size_t)CELLS * HID * 4);
  float* m1   = (float*)alloc((size_t)CELLS * HID * 4);
  u16*   W0b  = (u16*)  alloc(2 * 128 * 256 * 2);
  u16*   W1b  = (u16*)  alloc(2 * 128 * 128 * 2);
  u16*   W2b  = (u16*)  alloc(2 * 128 * 128 * 2);
  u16*   W3b  = (u16*)  alloc(2 * 128 * 128 * 2);
  u16*   Wcb  = (u16*)  alloc(512 * 512 * 2);
  float* bp   = (float*)alloc(4 * 256 * 4);
  u16*   embp = (u16*)  alloc(384 * 2);
  float* swp  = (float*)alloc(128 * 4);
  // sort workspace
  int*   counts = (int*)alloc((size_t)2 * CELLS * 4);
  int*   Sarr   = (int*)alloc(((size_t)2 * CELLS + 1) * 4);
  int*   fill   = (int*)alloc((size_t)2 * CELLS * 4);
  int*   btot   = (int*)alloc(192 * 4);
  int*   boffs  = (int*)alloc(192 * 4);
  int*   ssrc   = (int*)alloc((size_t)2 * NE * 4);
  int*   sdst   = (int*)alloc((size_t)2 * NE * 4);

  prep_kernel<<<1670, 256, 0, stream>>>(W0, W1, W2, W3, b0, b1, b2, b3, Wih, Whh, embed, sw,
                                        W0b, W1b, W2b, W3b, Wcb, bp, embp, swp);
  init_kernel<<<(CELLS * HID) / 256, 256, 0, stream>>>(q, embp, xb, h, rc);

  // dst-sort both edge types
  hipMemsetAsync(counts, 0, (size_t)2 * CELLS * 4, stream);
  hipMemsetAsync(fill, 0, (size_t)2 * CELLS * 4, stream);
  hist_kernel<<<(2 * NE + 255) / 256, 256, 0, stream>>>(edst, counts);
  scan1_kernel<<<192, 1024, 0, stream>>>(counts, Sarr, btot);
  scan2_kernel<<<1, 256, 0, stream>>>(btot, boffs, Sarr);
  scan3_kernel<<<192, 1024, 0, stream>>>(Sarr, boffs);
  scatter_kernel<<<(2 * NE + 255) / 256, 256, 0, stream>>>(esrc, edst, Sarr, fill, ssrc, sdst);

  for (int step = 0; step < NSTEPS; ++step) {
    hipMemsetAsync(m0, 0, (size_t)CELLS * HID * 4, stream);
    hipMemsetAsync(m1, 0, (size_t)CELLS * HID * 4, stream);
    msg_kernel<<<dim3((NE + 127) / 128, 2), 128, 0, stream>>>(h, ssrc, sdst, Sarr,
                                                              W0b, W1b, W2b, W3b, bp, m0, m1);
    lstm_kernel<<<CELLS / 64, 512, 0, stream>>>(step, xb, m0, m1, h, rc, Wcb, swp, (float*)d_out);
  }
}

// Round 7
// 953.573 us; speedup vs baseline: 1.6111x; 1.1231x over previous
//
#include <hip/hip_runtime.h>

#define HID 128
#define CELLS 98304
#define NE 250000
#define NSTEPS 2

typedef __attribute__((ext_vector_type(8))) short short8;
typedef __attribute__((ext_vector_type(4))) short short4v;
typedef __attribute__((ext_vector_type(4))) float f32x4;
typedef unsigned short u16;

// pi permutation for msg's internal LDS tiles: stored slot s holds natural col permf(s)
__device__ __forceinline__ int permf(int s) { return ((s & 7) << 4) | (s >> 3); }

__device__ __forceinline__ u16 f2bf(float f) {
  unsigned int u = __builtin_bit_cast(unsigned int, f);
  u += 0x7fffu + ((u >> 16) & 1u);
  return (u16)(u >> 16);
}
__device__ __forceinline__ float bf2f(u16 s) {
  unsigned int u = ((unsigned int)s) << 16;
  return __builtin_bit_cast(float, u);
}
__device__ __forceinline__ float sigm(float x) { return 1.f / (1.f + __expf(-x)); }
__device__ __forceinline__ float tanha(float x) { return 1.f - 2.f / (__expf(2.f * x) + 1.f); }

// ---------------- prep: bf16-convert weights (K natural except W1-3 pi) ----------------
__global__ void prep_kernel(
    const float* __restrict__ W0, const float* __restrict__ W1,
    const float* __restrict__ W2, const float* __restrict__ W3,
    const float* __restrict__ b0, const float* __restrict__ b1,
    const float* __restrict__ b2, const float* __restrict__ b3,
    const float* __restrict__ Wih, const float* __restrict__ Whh,
    const float* __restrict__ embed, const float* __restrict__ sw,
    u16* __restrict__ W0b, u16* __restrict__ W1b,
    u16* __restrict__ W2b, u16* __restrict__ W3b,
    u16* __restrict__ Wcb, float* __restrict__ bp,
    u16* __restrict__ embp, float* __restrict__ swp)
{
  int idx = blockIdx.x * 256 + threadIdx.x;
  if (idx < 65536) {  // W0b [et][n][k] natural (h is natural-ordered)
    W0b[idx] = f2bf(W0[idx]);
    return;
  }
  idx -= 65536;
  if (idx < 98304) {  // W1b/W2b/W3b [et][n][s]: K pi-permuted to match msg LDS tiles
    int which = idx >> 15, r = idx & 32767;
    int s = r & 127, n = (r >> 7) & 127, et = r >> 14;
    const float* W = which == 0 ? W1 : (which == 1 ? W2 : W3);
    u16* Wb = which == 0 ? W1b : (which == 1 ? W2b : W3b);
    Wb[r] = f2bf(W[(et * 128 + n) * 128 + permf(s)]);
    return;
  }
  idx -= 98304;
  if (idx < 262144) {  // Wcat [n=512][k=512] = [Wih(x|m0|m1) | Whh], K natural
    int s = idx & 511, n = idx >> 9;
    int blk = s >> 7, s7 = s & 127;
    float v = (blk < 3) ? Wih[n * 384 + blk * 128 + s7] : Whh[n * 128 + s7];
    Wcb[idx] = f2bf(v);
    return;
  }
  idx -= 262144;
  if (idx < 1024) {  // biases [layer 0..3][et][slot] pi-order (consumed slot-wise in msg)
    int l = idx >> 8, r = idx & 255;
    int et = r >> 7, s = r & 127;
    const float* b = l == 0 ? b0 : (l == 1 ? b1 : (l == 2 ? b2 : b3));
    bp[idx] = b[et * 128 + permf(s)];
    return;
  }
  idx -= 1024;
  if (idx < 384) {  // embed natural bf16
    embp[idx] = f2bf(embed[idx]);
    return;
  }
  idx -= 384;
  if (idx < 128) swp[idx] = sw[idx];
}

// ---------------- init: x = embed[q] (natural, bf16), h = x, rc = 0 ----------------
__global__ void init_kernel(const int* __restrict__ q, const u16* __restrict__ embp,
                            u16* __restrict__ xb, u16* __restrict__ h, float* __restrict__ rc)
{
  int idx = blockIdx.x * 256 + threadIdx.x;
  int c = idx >> 7, s = idx & 127;
  u16 v = embp[q[c] * 128 + s];
  xb[idx] = v;
  h[idx] = v;
  rc[idx] = 0.f;
}

// ---------------- dst-sort pipeline: hist -> scan (2-level) -> scatter ----------------
__global__ void hist_kernel(const int* __restrict__ edst, int* __restrict__ counts)
{
  int idx = blockIdx.x * 256 + threadIdx.x;
  if (idx >= 2 * NE) return;
  int et = (idx >= NE) ? 1 : 0;
  atomicAdd(&counts[et * CELLS + edst[idx]], 1);
}

__global__ void scan1_kernel(const int* __restrict__ counts, int* __restrict__ S,
                             int* __restrict__ btot)
{
  __shared__ int sh[1024];
  const int t = threadIdx.x, b = blockIdx.x;
  const int i = b * 1024 + t;
  int v = counts[i];
  sh[t] = v;
  __syncthreads();
  int acc = v;
  for (int off = 1; off < 1024; off <<= 1) {
    int add = (t >= off) ? sh[t - off] : 0;
    __syncthreads();
    acc += add;
    sh[t] = acc;
    __syncthreads();
  }
  S[i] = acc - v;  // block-local exclusive
  if (t == 1023) btot[b] = acc;
}

__global__ void scan2_kernel(const int* __restrict__ btot, int* __restrict__ boffs,
                             int* __restrict__ S)
{
  __shared__ int sh[256];
  const int t = threadIdx.x;
  int v = (t < 192) ? btot[t] : 0;
  sh[t] = v;
  __syncthreads();
  int acc = v;
  for (int off = 1; off < 256; off <<= 1) {
    int add = (t >= off) ? sh[t - off] : 0;
    __syncthreads();
    acc += add;
    sh[t] = acc;
    __syncthreads();
  }
  if (t < 192) boffs[t] = acc - v;
  if (t == 0) S[2 * CELLS] = 2 * NE;
}

__global__ void scan3_kernel(int* __restrict__ S, const int* __restrict__ boffs)
{
  const int i = blockIdx.x * 1024 + threadIdx.x;
  S[i] += boffs[blockIdx.x];
}

__global__ void scatter_kernel(const int* __restrict__ esrc, const int* __restrict__ edst,
                               const int* __restrict__ S, int* __restrict__ fill,
                               int* __restrict__ ssrc, int* __restrict__ sdst)
{
  int idx = blockIdx.x * 256 + threadIdx.x;
  if (idx >= 2 * NE) return;
  int et = (idx >= NE) ? 1 : 0;
  int d = edst[idx];
  int pos = atomicAdd(&fill[et * CELLS + d], 1);
  int slot = S[et * CELLS + d] - et * NE + pos;  // et-local sorted slot
  sdst[et * NE + slot] = d;
  ssrc[et * NE + slot] = esrc[idx];
}

// bias+relu+pack this wave's 64 cols into the shared pi-slot LDS tile.
// slot = c*8 + w*4 + nt holds natural col (w*4+nt)*16 + c  (== permf(slot)).
__device__ __forceinline__ void store_half(f32x4 (&acc)[4][4], const float* __restrict__ bl,
                                           u16* __restrict__ tile, int w, int q, int c)
{
  float bias[4];
  #pragma unroll
  for (int nt = 0; nt < 4; ++nt) bias[nt] = bl[c * 8 + w * 4 + nt];
  #pragma unroll
  for (int mt = 0; mt < 4; ++mt) {
    #pragma unroll
    for (int r = 0; r < 4; ++r) {
      const int rowl = mt * 16 + 4 * q + r;
      short4v t;
      #pragma unroll
      for (int nt = 0; nt < 4; ++nt) {
        float v = acc[mt][nt][r] + bias[nt];
        v = v > 0.f ? v : 0.f;
        t[nt] = (short)f2bf(v);
      }
      *(short4v*)(tile + rowl * 128 + ((c ^ (rowl & 15)) << 3) + w * 4) = t;
    }
  }
}

// ---------------- fused 4-layer edge MLP + sorted segmented-sum scatter ----------------
// block: 2 waves SHARING one 64-edge window (N-split: wave w owns cols [w*64, w*64+64)).
// acc[4][4] = 64 AGPR -> ~3 waves/SIMD; 16KB LDS. m stored natural-order.
__launch_bounds__(128, 3)
__global__ void msg_kernel(
    const u16* __restrict__ h,
    const int* __restrict__ ssrc, const int* __restrict__ sdst,
    const int* __restrict__ S,
    const u16* __restrict__ W0b, const u16* __restrict__ W1b,
    const u16* __restrict__ W2b, const u16* __restrict__ W3b,
    const float* __restrict__ bp,
    float* __restrict__ m0, float* __restrict__ m1)
{
  __shared__ u16 tile[64 * 128];  // 16KB, shared between the 2 waves
  const int et = blockIdx.y;
  const int tid = threadIdx.x;
  const int w = tid >> 6, lane = tid & 63, q = lane >> 4, c = lane & 15;
  const int ebase = blockIdx.x * 64;  // one 64-edge window per block
  const int* __restrict__ src = ssrc + et * NE;
  const int* __restrict__ dst = sdst + et * NE;
  const u16* __restrict__ Wl0 = W0b + et * 32768;
  const u16* __restrict__ Wl[3] = {W1b + et * 16384, W2b + et * 16384, W3b + et * 16384};
  float* __restrict__ msgs = (et == 0) ? m0 : m1;

  int rowS[4], rowD[4];
  #pragma unroll
  for (int mt = 0; mt < 4; ++mt) {
    int e = ebase + mt * 16 + c;
    if (e >= NE) e = NE - 1;
    rowS[mt] = src[e];
    rowD[mt] = dst[e];
  }

  // run structure (wave-uniform). Cross-lane ops unconditional (round-3 lesson).
  const int eL = ebase + lane;
  const int dval = (eL < NE) ? dst[eL] : -1;
  int rpS = 0, rpE = 0;
  if (dval >= 0) {
    rpS = S[et * CELLS + dval] - et * NE;
    rpE = S[et * CELLS + dval + 1] - et * NE;
  }
  const int dlagged = __shfl_up(dval, 1);
  const bool headp = (lane == 0) | (dval != dlagged);
  const unsigned long long tails = (__ballot(headp) >> 1) | (1ull << 63);
  const unsigned long long intmask = __ballot(dval >= 0 && rpS >= ebase && rpE <= ebase + 64);

  const f32x4 zf = {0.f, 0.f, 0.f, 0.f};
  f32x4 acc[4][4];
  #pragma unroll
  for (int mt = 0; mt < 4; ++mt)
    #pragma unroll
    for (int nt = 0; nt < 4; ++nt) acc[mt][nt] = zf;

  // layer 0: K=256 = [h[src] | h[dst]] natural; A from global, B = this wave's 64 cols
  #pragma unroll
  for (int ks = 0; ks < 8; ++ks) {
    const int kq = ks * 32 + q * 8;
    short8 a[4], b[4];
    #pragma unroll
    for (int mt = 0; mt < 4; ++mt) {
      int row = (ks < 4) ? rowS[mt] : rowD[mt];
      a[mt] = *(const short8*)(h + row * HID + (kq & 127));
    }
    #pragma unroll
    for (int nt = 0; nt < 4; ++nt)
      b[nt] = *(const short8*)(Wl0 + (w * 64 + nt * 16 + c) * 256 + kq);
    #pragma unroll
    for (int mt = 0; mt < 4; ++mt)
      #pragma unroll
      for (int nt = 0; nt < 4; ++nt)
        acc[mt][nt] = __builtin_amdgcn_mfma_f32_16x16x32_bf16(a[mt], b[nt], acc[mt][nt], 0, 0, 0);
  }
  store_half(acc, bp + et * 128, tile, w, q, c);
  __syncthreads();

  // layers 1..3: A from shared tile (pi slots), B K-pi matched
  #pragma unroll
  for (int l = 0; l < 3; ++l) {
    #pragma unroll
    for (int mt = 0; mt < 4; ++mt)
      #pragma unroll
      for (int nt = 0; nt < 4; ++nt) acc[mt][nt] = zf;
    #pragma unroll
    for (int ks = 0; ks < 4; ++ks) {
      const int kq = ks * 32 + q * 8;
      const int blk = ks * 4 + q;
      short8 a[4], b[4];
      #pragma unroll
      for (int mt = 0; mt < 4; ++mt)
        a[mt] = *(const short8*)(tile + (mt * 16 + c) * 128 + ((blk ^ c) << 3));
      #pragma unroll
      for (int nt = 0; nt < 4; ++nt)
        b[nt] = *(const short8*)(Wl[l] + (w * 64 + nt * 16 + c) * 128 + kq);
      #pragma unroll
      for (int mt = 0; mt < 4; ++mt)
        #pragma unroll
        for (int nt = 0; nt < 4; ++nt)
          acc[mt][nt] = __builtin_amdgcn_mfma_f32_16x16x32_bf16(a[mt], b[nt], acc[mt][nt], 0, 0, 0);
    }
    if (l < 2) {
      __syncthreads();  // all tile reads done
      store_half(acc, bp + (l + 1) * 256 + et * 128, tile, w, q, c);
      __syncthreads();  // writes visible
    }
  }

  // In-register segmented reduction over the sorted window.
  // Row j lives in lanes with q == (j>>2)&3 at acc[j>>4][*][j&3].
  // Bias folded as run_len * bias (reference adds b3 per edge, then sums).
  float bias[4];
  #pragma unroll
  for (int nt = 0; nt < 4; ++nt) bias[nt] = bp[3 * 256 + et * 128 + c * 8 + w * 4 + nt];

  float p0 = 0.f, p1 = 0.f, p2 = 0.f, p3 = 0.f;
  int jstart = 0;
  #pragma unroll
  for (int j = 0; j < 64; ++j) {
    const int mtj = j >> 4, qj = (j >> 2) & 3, rj = j & 3;
    const bool mine = (q == qj);
    p0 += mine ? acc[mtj][0][rj] : 0.f;
    p1 += mine ? acc[mtj][1][rj] : 0.f;
    p2 += mine ? acc[mtj][2][rj] : 0.f;
    p3 += mine ? acc[mtj][3][rj] : 0.f;
    if ((tails >> j) & 1) {  // wave-uniform flush
      const int d = __builtin_amdgcn_readlane(dval, j);
      const float len = (float)(j + 1 - jstart);
      float t0 = p0, t1 = p1, t2 = p2, t3 = p3;
      t0 += __shfl_xor(t0, 16); t0 += __shfl_xor(t0, 32);
      t1 += __shfl_xor(t1, 16); t1 += __shfl_xor(t1, 32);
      t2 += __shfl_xor(t2, 16); t2 += __shfl_xor(t2, 32);
      t3 += __shfl_xor(t3, 16); t3 += __shfl_xor(t3, 32);
      if (d >= 0 && q == 0) {
        float* mp = msgs + (size_t)d * HID + w * 64 + c;
        t0 += len * bias[0]; t1 += len * bias[1]; t2 += len * bias[2]; t3 += len * bias[3];
        if ((intmask >> j) & 1) {
          mp[0] = t0; mp[16] = t1; mp[32] = t2; mp[48] = t3;
        } else {
          atomicAdd(mp, t0); atomicAdd(mp + 16, t1);
          atomicAdd(mp + 32, t2); atomicAdd(mp + 48, t3);
        }
      }
      p0 = p1 = p2 = p3 = 0.f;
      jstart = j + 1;
    }
  }
}

// ---------------- fused LSTM: gates GEMM (K=512) + in-register activations + score -------
// block: 8 waves, 64 cells. Wave wf owns feature cols [wf*16, wf*16+16) for ALL 4 gates:
// acc[mt][g] -> i,f,g,o for (cell, feature) live in the SAME lane => no gate exchange.
__launch_bounds__(512, 4)
__global__ void lstm_kernel(
    const int step,
    const u16* __restrict__ xb, const float* __restrict__ mm0, const float* __restrict__ mm1,
    u16* __restrict__ h, float* __restrict__ rc,
    const u16* __restrict__ Wcb, const float* __restrict__ swp,
    float* __restrict__ out)
{
  __shared__ u16 at[64 * 512];  // 64KB: A-tile (natural K), later reused for score partials
  const int tid = threadIdx.x;
  const int cb = blockIdx.x * 64;

  // stage A = [x | m0 | m1 | rh] bf16, natural order (m is natural now)
  for (int base = tid * 8; base < 64 * 512; base += 4096) {
    const int cl = base >> 9, s = base & 511;
    const int cell = cb + cl;
    short8 t;
    if (s < 128) {
      t = *(const short8*)(xb + cell * 128 + s);
    } else if (s < 384) {
      const float* mp = (s < 256 ? mm0 : mm1) + cell * 128 + (s & 127);
      f32x4 lo = *(const f32x4*)(mp);
      f32x4 hi = *(const f32x4*)(mp + 4);
      #pragma unroll
      for (int j = 0; j < 4; ++j) { t[j] = (short)f2bf(lo[j]); t[4 + j] = (short)f2bf(hi[j]); }
    } else if (step == 0) {
      #pragma unroll
      for (int j = 0; j < 8; ++j) t[j] = 0;
    } else {
      t = *(const short8*)(h + cell * 128 + (s & 127));
    }
    const int blk = s >> 3;
    const int blks = (blk & 48) | ((blk ^ cl) & 15);
    *(short8*)(at + cl * 512 + blks * 8) = t;
  }
  __syncthreads();

  const int w = tid >> 6, lane = tid & 63, q = lane >> 4, c = lane & 15;
  const int wf = w;  // feature-16 group
  const f32x4 zf = {0.f, 0.f, 0.f, 0.f};
  f32x4 acc[4][4];  // [cell-tile][gate]
  #pragma unroll
  for (int mt = 0; mt < 4; ++mt)
    #pragma unroll
    for (int g = 0; g < 4; ++g) acc[mt][g] = zf;

  #pragma unroll
  for (int ks = 0; ks < 16; ++ks) {
    const int kq = ks * 32 + q * 8;
    const int blk = kq >> 3;
    short8 a[4], b[4];
    #pragma unroll
    for (int mt = 0; mt < 4; ++mt) {
      const int row = mt * 16 + c;
      const int blks = (blk & 48) | ((blk ^ c) & 15);
      a[mt] = *(const short8*)(at + row * 512 + blks * 8);
    }
    #pragma unroll
    for (int g = 0; g < 4; ++g)
      b[g] = *(const short8*)(Wcb + (g * 128 + wf * 16 + c) * 512 + kq);
    #pragma unroll
    for (int mt = 0; mt < 4; ++mt)
      #pragma unroll
      for (int g = 0; g < 4; ++g)
        acc[mt][g] = __builtin_amdgcn_mfma_f32_16x16x32_bf16(a[mt], b[g], acc[mt][g], 0, 0, 0);
  }
  __syncthreads();  // tile reads done everywhere; safe to reuse for score partials

  // in-register LSTM epilogue: lane (q,c) per (mt,r): cell = mt*16+4q+r, feat = wf*16+c
  const float swc = swp[wf * 16 + c];
  float* pt = (float*)at;  // [8 waves][64 cells] score partials
  #pragma unroll
  for (int mt = 0; mt < 4; ++mt) {
    #pragma unroll
    for (int r = 0; r < 4; ++r) {
      const int cl = mt * 16 + 4 * q + r;
      const int cell = cb + cl;
      const float ig = sigm(acc[mt][0][r]);
      const float fg = sigm(acc[mt][1][r]);
      const float gg = tanha(acc[mt][2][r]);
      const float og = sigm(acc[mt][3][r]);
      float* rcp = rc + (size_t)cell * HID + wf * 16 + c;
      const float nc = fg * rcp[0] + ig * gg;
      const float nhv = og * tanha(nc);
      rcp[0] = nc;
      h[(size_t)cell * HID + wf * 16 + c] = f2bf(nhv);
      float v = nhv * swc;  // score partial, reduce over c (16 feats)
      v += __shfl_xor(v, 1); v += __shfl_xor(v, 2);
      v += __shfl_xor(v, 4); v += __shfl_xor(v, 8);
      if (c == 0) pt[wf * 64 + cl] = v;
    }
  }
  __syncthreads();
  if (tid < 64) {
    float s = 0.f;
    #pragma unroll
    for (int ww = 0; ww < 8; ++ww) s += pt[ww * 64 + tid];
    out[step * CELLS + cb + tid] = s;
  }
}

extern "C" void kernel_launch(void* const* d_in, const int* in_sizes, int n_in,
                              void* d_out, int out_size, void* d_ws, size_t ws_size,
                              hipStream_t stream)
{
  const int* q      = (const int*)d_in[0];
  const int* esrc   = (const int*)d_in[1];
  const int* edst   = (const int*)d_in[2];
  const float* embed= (const float*)d_in[3];
  const float* W0   = (const float*)d_in[4];
  const float* b0   = (const float*)d_in[5];
  const float* W1   = (const float*)d_in[6];
  const float* b1   = (const float*)d_in[7];
  const float* W2   = (const float*)d_in[8];
  const float* b2   = (const float*)d_in[9];
  const float* W3   = (const float*)d_in[10];
  const float* b3   = (const float*)d_in[11];
  const float* Wih  = (const float*)d_in[12];
  const float* Whh  = (const float*)d_in[13];
  const float* sw   = (const float*)d_in[14];

  char* ws = (char*)d_ws;
  size_t off = 0;
  auto alloc = [&](size_t bytes) {
    void* p = ws + off;
    off += (bytes + 255) & ~(size_t)255;
    return p;
  };
  u16*   h    = (u16*)  alloc((size_t)CELLS * HID * 2);
  u16*   xb   = (u16*)  alloc((size_t)CELLS * HID * 2);
  float* rc   = (float*)alloc((size_t)CELLS * HID * 4);
  float* m0   = (float*)alloc((size_t)CELLS * HID * 4);
  float* m1   = (float*)alloc((size_t)CELLS * HID * 4);
  u16*   W0b  = (u16*)  alloc(2 * 128 * 256 * 2);
  u16*   W1b  = (u16*)  alloc(2 * 128 * 128 * 2);
  u16*   W2b  = (u16*)  alloc(2 * 128 * 128 * 2);
  u16*   W3b  = (u16*)  alloc(2 * 128 * 128 * 2);
  u16*   Wcb  = (u16*)  alloc(512 * 512 * 2);
  float* bp   = (float*)alloc(4 * 256 * 4);
  u16*   embp = (u16*)  alloc(384 * 2);
  float* swp  = (float*)alloc(128 * 4);
  // sort workspace
  int*   counts = (int*)alloc((size_t)2 * CELLS * 4);
  int*   Sarr   = (int*)alloc(((size_t)2 * CELLS + 1) * 4);
  int*   fill   = (int*)alloc((size_t)2 * CELLS * 4);
  int*   btot   = (int*)alloc(192 * 4);
  int*   boffs  = (int*)alloc(192 * 4);
  int*   ssrc   = (int*)alloc((size_t)2 * NE * 4);
  int*   sdst   = (int*)alloc((size_t)2 * NE * 4);

  prep_kernel<<<1670, 256, 0, stream>>>(W0, W1, W2, W3, b0, b1, b2, b3, Wih, Whh, embed, sw,
                                        W0b, W1b, W2b, W3b, Wcb, bp, embp, swp);
  init_kernel<<<(CELLS * HID) / 256, 256, 0, stream>>>(q, embp, xb, h, rc);

  // dst-sort both edge types
  hipMemsetAsync(counts, 0, (size_t)2 * CELLS * 4, stream);
  hipMemsetAsync(fill, 0, (size_t)2 * CELLS * 4, stream);
  hist_kernel<<<(2 * NE + 255) / 256, 256, 0, stream>>>(edst, counts);
  scan1_kernel<<<192, 1024, 0, stream>>>(counts, Sarr, btot);
  scan2_kernel<<<1, 256, 0, stream>>>(btot, boffs, Sarr);
  scan3_kernel<<<192, 1024, 0, stream>>>(Sarr, boffs);
  scatter_kernel<<<(2 * NE + 255) / 256, 256, 0, stream>>>(esrc, edst, Sarr, fill, ssrc, sdst);

  for (int step = 0; step < NSTEPS; ++step) {
    hipMemsetAsync(m0, 0, (size_t)CELLS * HID * 4, stream);
    hipMemsetAsync(m1, 0, (size_t)CELLS * HID * 4, stream);
    msg_kernel<<<dim3((NE + 63) / 64, 2), 128, 0, stream>>>(h, ssrc, sdst, Sarr,
                                                            W0b, W1b, W2b, W3b, bp, m0, m1);
    lstm_kernel<<<CELLS / 64, 512, 0, stream>>>(step, xb, m0, m1, h, rc, Wcb, swp, (float*)d_out);
  }
}